// Round 9
// baseline (667.390 us; speedup 1.0000x reference)
//
#include <hip/hip_runtime.h>
#include <float.h>

// Sparsemax attention, fp32 in/out. B=64, Lq=Lk=1024, D=64.
// d_out = out[B,Lq,D] ++ attn[B,Lq,Lk], fp32.
//
// R9 = R8 with two changes:
//  A) MFMA operands swapped (A=K-frag, B=Q-frag): C row = key, so the 4 acc
//     regs are 4 CONSECUTIVE KEYS of one q-row -> one 8-B ushort4 store per
//     (kt,g) instead of 32 scattered 2-B stores per kt (barrier vmcnt drain).
//     Fragment reads unchanged (operand layouts are symmetric for 16x16x32).
//  B) attn is zeroed via hipMemsetAsync (~42us at 6.4 TB/s); B scatters only
//     the ~10 support entries per row instead of storing all 1024. Cuts B's
//     write traffic 278 MB -> ~18 MB. Only when S is in d_ws (fallback path
//     keeps R8's full-write behavior).

#define BATCH    64
#define SEQQ     1024
#define SEQK     1024
#define DHEAD    64

typedef short short8 __attribute__((ext_vector_type(8)));
typedef float f32x4  __attribute__((ext_vector_type(4)));
typedef unsigned short us4v __attribute__((ext_vector_type(4)));

typedef const __attribute__((address_space(1))) unsigned int as1_cuint;
typedef __attribute__((address_space(3))) unsigned int as3_uint;
typedef __attribute__((address_space(3))) unsigned char as3_uchar;

__device__ __forceinline__ unsigned short bf16_rne(float f) {
    unsigned u = __float_as_uint(f);
    u += 0x7fffu + ((u >> 16) & 1u);
    return (unsigned short)(u >> 16);
}

__device__ __forceinline__ void cvt_hilo8(const float* fv, float scale,
                                          short8* hi, short8* lo) {
    #pragma unroll
    for (int j = 0; j < 8; ++j) {
        float f = fv[j] * scale;
        unsigned short hb = bf16_rne(f);
        float hf = __uint_as_float((unsigned)hb << 16);
        (*hi)[j] = (short)hb;
        (*lo)[j] = (short)bf16_rne(f - hf);
    }
}

// ---- mask dtype detector: 1-byte bools vs int32 0/1 (proven R1-R8) --------
__global__ void detect_mask_fmt(const unsigned char* __restrict__ m,
                                int* __restrict__ flag) {
    __shared__ int s_found;
    if (threadIdx.x == 0) s_found = 0;
    __syncthreads();
    int found = 0;
    for (int o = threadIdx.x; o < 65536; o += 256) {
        if ((o & 3) != 0 && m[o] != 0) found = 1;
    }
    if (found) atomicOr(&s_found, 1);
    __syncthreads();
    if (threadIdx.x == 0) *flag = s_found;   // 1 => bytes, 0 => int32
}

// ---- kernel 0: K -> hi/lo bf16, pre-swizzled in klds tile layout ----------
__global__ __launch_bounds__(256) void kprep(
        const float* __restrict__ k, unsigned short* __restrict__ kbuf) {
    int gid  = blockIdx.x * 256 + threadIdx.x;    // [0, 64*1024*8)
    int db   = gid & 7;
    int keyg = (gid >> 3) & 1023;
    int b    = gid >> 13;
    int kt   = keyg >> 7;
    int key  = keyg & 127;

    const float4* src =
        (const float4*)(k + ((size_t)b * SEQK + keyg) * DHEAD + db * 8);
    float4 f0 = src[0], f1 = src[1];
    float fv[8] = {f0.x, f0.y, f0.z, f0.w, f1.x, f1.y, f1.z, f1.w};
    short8 hi, lo;
    cvt_hilo8(fv, 1.0f, &hi, &lo);

    unsigned short* tile = kbuf + (size_t)(b * 8 + kt) * 16384;
    int off = key * 64 + ((db ^ (key & 7)) * 8);   // ushort units
    *(short8*)(tile + off)        = hi;
    *(short8*)(tile + 8192 + off) = lo;
}

// ---- kernel A (fast path): scores via MFMA, DMA-staged K tiles ------------
// grid 1024: x = qt*64 + b (x%8 = b%8 -> per-batch XCD pinning).
// MFMA: A-operand = K fragment, B-operand = Q fragment.
// C layout: row (quad*4+r) = key-in-group, col (l15) = q-row-in-wave.
__global__ __launch_bounds__(256) void score_kernel_dma(
        const float* __restrict__ q, const unsigned short* __restrict__ kbuf,
        unsigned short* __restrict__ sbuf, int pitch) {
    const int lane = threadIdx.x & 63;
    const int wave = threadIdx.x >> 6;
    const int quad = lane >> 4;
    const int l15  = lane & 15;
    const int qt = blockIdx.x >> 6;
    const int b  = blockIdx.x & 63;

    __shared__ unsigned short klds[2 * 128 * 64];   // 32 KB

    // Q fragments once (B-operand): lane holds Q[row=l15][kc*32+quad*8+j]/8
    const float* qrow =
        q + ((size_t)b * SEQQ + qt * 64 + wave * 16 + l15) * DHEAD;
    short8 q_hi[2], q_lo[2];
    #pragma unroll
    for (int kc = 0; kc < 2; ++kc) {
        const float4* src = (const float4*)(qrow + kc * 32 + quad * 8);
        float4 f0 = src[0], f1 = src[1];
        float fv[8] = {f0.x, f0.y, f0.z, f0.w, f1.x, f1.y, f1.z, f1.w};
        cvt_hilo8(fv, 0.125f, &q_hi[kc], &q_lo[kc]);
    }

    // this lane's output row = the wave's q-row l15
    unsigned short* srow =
        sbuf + ((size_t)b * SEQQ + qt * 64 + wave * 16 + l15) * (size_t)pitch;

    for (int kt = 0; kt < 8; ++kt) {
        __syncthreads();   // guard klds reuse across kt iterations
        const unsigned char* gtile =
            (const unsigned char*)(kbuf + (size_t)(b * 8 + kt) * 16384);
        {
            unsigned base = wave * 8192 + lane * 16;
            #pragma unroll
            for (int j = 0; j < 8; ++j) {
                unsigned off = base + j * 1024;
                as1_cuint* gp = (as1_cuint*)(gtile + off);
                as3_uint*  lp = (as3_uint*)((as3_uchar*)klds +
                                            (wave * 8192 + j * 1024));
                __builtin_amdgcn_global_load_lds(gp, lp, 16, 0, 0);
            }
        }
        __syncthreads();

        #pragma unroll
        for (int g = 0; g < 8; ++g) {
            int key = g * 16 + l15;   // A-operand m-index = key
            short8 k_hi[2], k_lo[2];
            #pragma unroll
            for (int kc = 0; kc < 2; ++kc) {
                int db  = kc * 4 + quad;
                int off = key * 64 + ((db ^ (key & 7)) * 8);
                k_hi[kc] = *(const short8*)(klds + off);
                k_lo[kc] = *(const short8*)(klds + 8192 + off);
            }
            f32x4 acc = {0.f, 0.f, 0.f, 0.f};
            #pragma unroll
            for (int kc = 0; kc < 2; ++kc) {
                acc = __builtin_amdgcn_mfma_f32_16x16x32_bf16(k_hi[kc], q_hi[kc], acc, 0, 0, 0);
                acc = __builtin_amdgcn_mfma_f32_16x16x32_bf16(k_hi[kc], q_lo[kc], acc, 0, 0, 0);
                acc = __builtin_amdgcn_mfma_f32_16x16x32_bf16(k_lo[kc], q_hi[kc], acc, 0, 0, 0);
            }
            // C: row quad*4+r = key g*16+quad*4+r, col l15 = q-row.
            // 4 consecutive keys of one row -> one 8-B packed store.
            us4v pk = {bf16_rne(acc[0]), bf16_rne(acc[1]),
                       bf16_rne(acc[2]), bf16_rne(acc[3])};
            *(us4v*)(srow + kt * 128 + g * 16 + quad * 4) = pk;
        }
    }
}

// ---- kernel A (fallback): cvt-in-loop version, same operand swap ----------
__global__ __launch_bounds__(256) void score_kernel_cvt(
        const float* __restrict__ q, const float* __restrict__ k,
        unsigned short* __restrict__ sbuf, int pitch) {
    const int lane = threadIdx.x & 63;
    const int wave = threadIdx.x >> 6;
    const int quad = lane >> 4;
    const int l15  = lane & 15;
    const int qt = blockIdx.x >> 6;
    const int b  = blockIdx.x & 63;

    __shared__ unsigned short klds[2 * 128 * 64];

    const float* qrow =
        q + ((size_t)b * SEQQ + qt * 64 + wave * 16 + l15) * DHEAD;
    short8 q_hi[2], q_lo[2];
    #pragma unroll
    for (int kc = 0; kc < 2; ++kc) {
        const float4* src = (const float4*)(qrow + kc * 32 + quad * 8);
        float4 f0 = src[0], f1 = src[1];
        float fv[8] = {f0.x, f0.y, f0.z, f0.w, f1.x, f1.y, f1.z, f1.w};
        cvt_hilo8(fv, 0.125f, &q_hi[kc], &q_lo[kc]);
    }

    const float* kb = k + (size_t)b * SEQK * DHEAD;
    unsigned short* srow =
        sbuf + ((size_t)b * SEQQ + qt * 64 + wave * 16 + l15) * (size_t)pitch;

    for (int kt = 0; kt < 8; ++kt) {
        __syncthreads();
        const float* kbase = kb + (size_t)kt * 128 * DHEAD;
        #pragma unroll
        for (int it = 0; it < 4; ++it) {
            int e   = threadIdx.x + 256 * it;
            int key = e >> 3, db = e & 7;
            const float4* src = (const float4*)(kbase + key * DHEAD + db * 8);
            float4 f0 = src[0], f1 = src[1];
            float fv[8] = {f0.x, f0.y, f0.z, f0.w, f1.x, f1.y, f1.z, f1.w};
            short8 hi, lo;
            cvt_hilo8(fv, 1.0f, &hi, &lo);
            int off = key * 64 + ((db ^ (key & 7)) * 8);
            *(short8*)(klds + off)        = hi;
            *(short8*)(klds + 8192 + off) = lo;
        }
        __syncthreads();

        #pragma unroll
        for (int g = 0; g < 8; ++g) {
            int key = g * 16 + l15;
            short8 k_hi[2], k_lo[2];
            #pragma unroll
            for (int kc = 0; kc < 2; ++kc) {
                int db  = kc * 4 + quad;
                int off = key * 64 + ((db ^ (key & 7)) * 8);
                k_hi[kc] = *(const short8*)(klds + off);
                k_lo[kc] = *(const short8*)(klds + 8192 + off);
            }
            f32x4 acc = {0.f, 0.f, 0.f, 0.f};
            #pragma unroll
            for (int kc = 0; kc < 2; ++kc) {
                acc = __builtin_amdgcn_mfma_f32_16x16x32_bf16(k_hi[kc], q_hi[kc], acc, 0, 0, 0);
                acc = __builtin_amdgcn_mfma_f32_16x16x32_bf16(k_hi[kc], q_lo[kc], acc, 0, 0, 0);
                acc = __builtin_amdgcn_mfma_f32_16x16x32_bf16(k_lo[kc], q_hi[kc], acc, 0, 0, 0);
            }
            us4v pk = {bf16_rne(acc[0]), bf16_rne(acc[1]),
                       bf16_rne(acc[2]), bf16_rne(acc[3])};
            *(us4v*)(srow + kt * 128 + g * 16 + quad * 4) = pk;
        }
    }
}

// ---- kernel B: sparsemax + sparse PV, one wave per row --------------------
// full_write=0: attn pre-zeroed by memset; scatter only support entries.
__global__ __launch_bounds__(256) void sparsemax_pv(
        const float* __restrict__ v, const void* __restrict__ mask,
        const int* __restrict__ fmt_flag,
        float* __restrict__ out, float* __restrict__ attn,
        const unsigned short* __restrict__ sbuf, int pitch, int full_write) {
    const int lane = threadIdx.x & 63;
    const int wave = threadIdx.x >> 6;
    const int row  = blockIdx.x * 4 + wave;
    const int b    = row >> 10;
    float* arow = attn + (size_t)row * SEQK;
    const int mask_is_byte = fmt_flag ? *fmt_flag : 1;

    __shared__ float pbuf[4][SEQK];   // per-wave p values, 16 KB total

    // lane holds keys 4*lane + 256*t + c (coalesced 8B, nontemporal)
    const us4v* s4 = (const us4v*)(sbuf + (size_t)row * (size_t)pitch);
    float s[16];
    #pragma unroll
    for (int t = 0; t < 4; ++t) {
        us4v u = __builtin_nontemporal_load(s4 + lane + 64 * t);
        s[4*t+0] = __uint_as_float((unsigned)u[0] << 16);
        s[4*t+1] = __uint_as_float((unsigned)u[1] << 16);
        s[4*t+2] = __uint_as_float((unsigned)u[2] << 16);
        s[4*t+3] = __uint_as_float((unsigned)u[3] << 16);
    }
    if (mask_is_byte) {
        const unsigned* m32 =
            (const unsigned*)((const unsigned char*)mask + (size_t)row * SEQK);
        #pragma unroll
        for (int t = 0; t < 4; ++t) {
            unsigned m = __builtin_nontemporal_load(m32 + lane + 64 * t);
            if (m & 0x000000ffu) s[4*t+0] = -FLT_MAX;
            if (m & 0x0000ff00u) s[4*t+1] = -FLT_MAX;
            if (m & 0x00ff0000u) s[4*t+2] = -FLT_MAX;
            if (m & 0xff000000u) s[4*t+3] = -FLT_MAX;
        }
    } else {
        const int* mi = (const int*)mask + (size_t)row * SEQK;
        #pragma unroll
        for (int t = 0; t < 4; ++t) {
            int m0 = __builtin_nontemporal_load(mi + 4 * (lane + 64 * t) + 0);
            int m1 = __builtin_nontemporal_load(mi + 4 * (lane + 64 * t) + 1);
            int m2 = __builtin_nontemporal_load(mi + 4 * (lane + 64 * t) + 2);
            int m3 = __builtin_nontemporal_load(mi + 4 * (lane + 64 * t) + 3);
            if (m0) s[4*t+0] = -FLT_MAX;
            if (m1) s[4*t+1] = -FLT_MAX;
            if (m2) s[4*t+2] = -FLT_MAX;
            if (m3) s[4*t+3] = -FLT_MAX;
        }
    }

    float mx = -FLT_MAX;
    #pragma unroll
    for (int i = 0; i < 16; ++i) mx = fmaxf(mx, s[i]);
    #pragma unroll
    for (int off = 32; off >= 1; off >>= 1)
        mx = fmaxf(mx, __shfl_xor(mx, off, 64));

    if (mx <= -FLT_MAX) {   // fully masked row -> zeros
        if (full_write) {
            f32x4 z = {0.f, 0.f, 0.f, 0.f};
            #pragma unroll
            for (int t = 0; t < 4; ++t)
                __builtin_nontemporal_store(z, (f32x4*)arow + lane + 64 * t);
        }
        out[(size_t)row * DHEAD + lane] = 0.f;
        return;
    }

    // Michelot: seed thr = mx-1 (tau* >= mx-1); A shrinks to exact support.
    float thr = mx - 1.0f, tau = 0.f;
    int cnt_prev = -1;
    for (int it = 0; it < 32; ++it) {
        float lsum = 0.f; int lcnt = 0;
        #pragma unroll
        for (int i = 0; i < 16; ++i)
            if (s[i] > thr) { lsum += s[i]; lcnt++; }
        #pragma unroll
        for (int off = 32; off >= 1; off >>= 1) {
            lsum += __shfl_xor(lsum, off, 64);
            lcnt += __shfl_xor(lcnt, off, 64);
        }
        tau = (lsum - 1.0f) / (float)lcnt;
        if (lcnt == cnt_prev) break;
        cnt_prev = lcnt;
        thr = tau;
    }

    float p[16];
    #pragma unroll
    for (int i = 0; i < 16; ++i) {
        float pv = s[i] - tau;
        p[i] = pv > 0.f ? pv : 0.f;
    }
    #pragma unroll
    for (int t = 0; t < 4; ++t) {
        f32x4 f = {p[4*t+0], p[4*t+1], p[4*t+2], p[4*t+3]};
        if (full_write)
            __builtin_nontemporal_store(f, (f32x4*)arow + lane + 64 * t);
        *(f32x4*)&pbuf[wave][4 * (lane + 64 * t)] = f;
    }
    if (!full_write) {
        // attn pre-zeroed: scatter only support entries (~10/row total)
        #pragma unroll
        for (int t = 0; t < 4; ++t) {
            #pragma unroll
            for (int c = 0; c < 4; ++c) {
                float pv = p[4*t+c];
                if (pv > 0.f) arow[4 * (lane + 64 * t) + c] = pv;
            }
        }
    }

    // sparse PV: group-of-4 extraction, independent v-loads in flight.
    const float* vbase = v + (size_t)b * SEQK * DHEAD;
    float oacc = 0.f;
    #pragma unroll
    for (int t = 0; t < 4; ++t) {
        #pragma unroll
        for (int c = 0; c < 4; ++c) {
            int i = 4 * t + c;
            unsigned long long mb = __ballot(p[i] > 0.f);
            while (mb) {
                int k0, k1 = -1, k2 = -1, k3 = -1;
                k0 = __ffsll(mb) - 1; mb &= mb - 1;
                if (mb) { k1 = __ffsll(mb) - 1; mb &= mb - 1; }
                if (mb) { k2 = __ffsll(mb) - 1; mb &= mb - 1; }
                if (mb) { k3 = __ffsll(mb) - 1; mb &= mb - 1; }
                int key0 = 4 * k0 + 256 * t + c;
                float pj0 = pbuf[wave][key0];
                float v0  = vbase[(size_t)key0 * DHEAD + lane];
                float pj1 = 0.f, pj2 = 0.f, pj3 = 0.f;
                float v1 = 0.f, v2 = 0.f, v3 = 0.f;
                if (k1 >= 0) {
                    int key1 = 4 * k1 + 256 * t + c;
                    pj1 = pbuf[wave][key1];
                    v1  = vbase[(size_t)key1 * DHEAD + lane];
                }
                if (k2 >= 0) {
                    int key2 = 4 * k2 + 256 * t + c;
                    pj2 = pbuf[wave][key2];
                    v2  = vbase[(size_t)key2 * DHEAD + lane];
                }
                if (k3 >= 0) {
                    int key3 = 4 * k3 + 256 * t + c;
                    pj3 = pbuf[wave][key3];
                    v3  = vbase[(size_t)key3 * DHEAD + lane];
                }
                oacc = fmaf(pj0, v0, oacc);
                if (k1 >= 0) oacc = fmaf(pj1, v1, oacc);
                if (k2 >= 0) oacc = fmaf(pj2, v2, oacc);
                if (k3 >= 0) oacc = fmaf(pj3, v3, oacc);
            }
        }
    }
    out[(size_t)row * DHEAD + lane] = oacc;
}

extern "C" void kernel_launch(void* const* d_in, const int* in_sizes, int n_in,
                              void* d_out, int out_size, void* d_ws, size_t ws_size,
                              hipStream_t stream) {
    const float* q = (const float*)d_in[0];
    const float* k = (const float*)d_in[1];
    const float* v = (const float*)d_in[2];
    const void*  m = d_in[3];

    float* out  = (float*)d_out;
    float* attn = out + (size_t)BATCH * SEQQ * DHEAD;

    int* flag = nullptr;
    if (ws_size >= sizeof(int)) {
        flag = (int*)d_ws;
        detect_mask_fmt<<<1, 256, 0, stream>>>((const unsigned char*)m, flag);
    }

    // ws layout: [0,16) flag | [16, 16+S) S bf16 | [16+S, 16+S+K) K hi/lo
    const size_t S_BYTES = (size_t)BATCH * SEQQ * SEQK * 2;          // 134 MB
    const size_t K_BYTES = (size_t)BATCH * SEQK * DHEAD * 2 * 2;     // 16 MB

    unsigned short* sbuf;
    int pitch;
    bool s_in_ws = ws_size >= 16 + S_BYTES;
    if (s_in_ws) {
        sbuf  = (unsigned short*)d_ws + 8;
        pitch = SEQK;
        // attn pre-zeroed here; kernel B scatters only the support
        hipMemsetAsync(attn, 0, (size_t)BATCH * SEQQ * SEQK * sizeof(float),
                       stream);
    } else {
        sbuf  = (unsigned short*)attn;   // in-place, strided (proven R5)
        pitch = 2 * SEQK;
    }

    bool k_in_ws = s_in_ws && ws_size >= 16 + S_BYTES + K_BYTES;
    if (k_in_ws) {
        unsigned short* kbuf =
            (unsigned short*)((char*)d_ws + 16 + S_BYTES);
        kprep<<<(BATCH * SEQK * 8) / 256, 256, 0, stream>>>(k, kbuf);
        score_kernel_dma<<<(SEQQ / 64) * BATCH, 256, 0, stream>>>(
            q, kbuf, sbuf, pitch);
    } else {
        score_kernel_cvt<<<(SEQQ / 64) * BATCH, 256, 0, stream>>>(
            q, k, sbuf, pitch);
    }

    sparsemax_pv<<<(BATCH * SEQQ) / 4, 256, 0, stream>>>(
        v, m, flag, out, attn, sbuf, pitch, s_in_ws ? 0 : 1);
}